// Round 3
// baseline (428.579 us; speedup 1.0000x reference)
//
#include <hip/hip_runtime.h>

// LIF recurrence: V = V + alpha*(I - V); spike = V>=1.0; V=0 on spike.
// N=65536 neurons (parallel), T=1024 steps (sequential per neuron).
// HBM stream: 256 MB read (~half L3-absorbed) + 256 MB write.
//
// R2 changes vs R1:
//  - plain stores instead of __builtin_nontemporal_store: NT no-allocates in
//    L2 and dribbles 64B chunks to HBM; write-back L2 coalesces full lines
//    (harness fillBuffer sustains 6.5 TB/s on this path, we saw 2.9 total).
//  - U 16->32: 32 outstanding loads/wave x 4 waves/CU = 32 KB/CU in flight,
//    ~3.5x the BW-latency product, covering latency inflation at saturation.
//  - keep loads-before-stores pipelining (R1's fix for vmcnt in-order
//    retirement: batch k+1 loads issue before batch k stores).

#define T_STEPS 1024
#define NUM_NEURONS 65536
#define N NUM_NEURONS
#define BLOCK 256
#define U 32

__global__ __launch_bounds__(BLOCK) void lif_kernel(const float* __restrict__ in,
                                                    float* __restrict__ out) {
    const int gid = blockIdx.x * BLOCK + threadIdx.x;  // [0, 65536)
    constexpr float alpha = 0.05f;  // DT/TAU = 1/20
    constexpr float vth = 1.0f;

    float V = 0.0f;  // V_RESET = 0
    const float* __restrict__ p = in + gid;
    float* __restrict__ q = out + gid;

    float I[U], J[U];

    // prologue: load first batch
#pragma unroll
    for (int u = 0; u < U; ++u) I[u] = p[(size_t)u * N];

    for (int t = 0; t < T_STEPS - U; t += U) {
        // prefetch batch t+U FIRST (program order before this batch's stores)
#pragma unroll
        for (int u = 0; u < U; ++u) J[u] = p[(size_t)(t + U + u) * N];
        // compute + store batch t
#pragma unroll
        for (int u = 0; u < U; ++u) {
            V = V + alpha * (I[u] - V);  // reference order, V_RESET = 0
            float s = (V >= vth) ? 1.0f : 0.0f;
            V = (V >= vth) ? 0.0f : V;
            q[(size_t)(t + u) * N] = s;
        }
#pragma unroll
        for (int u = 0; u < U; ++u) I[u] = J[u];
    }

    // epilogue: last batch (t = T_STEPS - U)
#pragma unroll
    for (int u = 0; u < U; ++u) {
        V = V + alpha * (I[u] - V);
        float s = (V >= vth) ? 1.0f : 0.0f;
        V = (V >= vth) ? 0.0f : V;
        q[(size_t)(T_STEPS - U + u) * N] = s;
    }
}

extern "C" void kernel_launch(void* const* d_in, const int* in_sizes, int n_in,
                              void* d_out, int out_size, void* d_ws, size_t ws_size,
                              hipStream_t stream) {
    const float* in = (const float*)d_in[0];
    float* out = (float*)d_out;
    lif_kernel<<<NUM_NEURONS / BLOCK, BLOCK, 0, stream>>>(in, out);
}